// Round 4
// baseline (286.329 us; speedup 1.0000x reference)
//
#include <hip/hip_runtime.h>
#include <stdint.h>

#define ENC_D 512
#define ATTN_D 512
#define STR_D 256
#define CELL_D 512
#define BATCH 64
#define SEQ 1024
#define NROWS (BATCH * SEQ)

typedef __bf16 bf16x8 __attribute__((ext_vector_type(8)));
typedef float f32x4 __attribute__((ext_vector_type(4)));

__device__ __forceinline__ unsigned short f2bf(float f) {
    unsigned int u = __float_as_uint(f);
    u += 0x7fffu + ((u >> 16) & 1u);   // RNE
    return (unsigned short)(u >> 16);
}

__device__ __forceinline__ void lds_cp16(void* l, const void* g) {
    __builtin_amdgcn_global_load_lds(
        (const __attribute__((address_space(1))) unsigned int*)g,
        (__attribute__((address_space(3))) unsigned int*)l, 16, 0, 0);
}

// Fused waitcnt+barrier as ONE asm with a memory clobber: the clobber is the
// compiler fence (bare builtins are not), the vmcnt(N) leaves the newest
// prefetch in flight across the barrier (no full drain).
#define BAR_VM4() asm volatile("s_waitcnt vmcnt(4)\n\ts_barrier" ::: "memory")

// ---------------------------------------------------------------------------
// Kernel 1 (fused): blocks 0..63   : WF = bf16(W_enc^T) fragment-linear,
//                                    K-SLICE-MAJOR: gi = ks*2048 + nt*64
//                                    + quad*16 + c  (32 KB contiguous/slice)
//                   blocks 64..831 : bias partials [jq][b][a] (12 slabs)
// ---------------------------------------------------------------------------
__global__ __launch_bounds__(256) void k_prep(const float* __restrict__ W,
                                              unsigned short* __restrict__ WF,
                                              const float* __restrict__ str,
                                              const float* __restrict__ cell,
                                              const float* __restrict__ Wstr,
                                              const float* __restrict__ Wcell,
                                              float* __restrict__ bpart) {
    __shared__ char smraw[64 * 68 * 2];        // 8704 B, reused per role
    const int bx = blockIdx.x, t = threadIdx.x;

    if (bx < 64) {
        unsigned short* T = (unsigned short*)smraw;   // [n_local][e_local] stride 68
        const int ei = bx >> 3, ni = bx & 7;
        const int e0 = ei * 64, n0 = ni * 64;
#pragma unroll
        for (int i = 0; i < 4; ++i) {
            const int idx = t + i * 256;
            const int r = idx >> 4, c4 = idx & 15;
            const float4 v = *(const float4*)(W + (size_t)(e0 + r) * ATTN_D + n0 + c4 * 4);
            T[(c4 * 4 + 0) * 68 + r] = f2bf(v.x);
            T[(c4 * 4 + 1) * 68 + r] = f2bf(v.y);
            T[(c4 * 4 + 2) * 68 + r] = f2bf(v.z);
            T[(c4 * 4 + 3) * 68 + r] = f2bf(v.w);
        }
        __syncthreads();
#pragma unroll
        for (int i = 0; i < 2; ++i) {
            const int q = t + i * 256;
            const int n = q >> 3, ge = q & 7;
            union { unsigned short s[8]; uint4 u; } o;
#pragma unroll
            for (int j = 0; j < 8; ++j) o.s[j] = T[n * 68 + ge * 8 + j];
            const int ng = n0 + n;
            const int g = ei * 8 + ge;
            const int nt = ng >> 4, c = ng & 15;
            const int ks = g >> 2, quad = g & 3;
            const int gi = ks * 2048 + nt * 64 + quad * 16 + c;   // k-slice-major
            *(uint4*)(WF + (size_t)gi * 8) = o.u;
        }
    } else {
        float* sj = (float*)smraw;          // 64 floats
        float* red = (float*)smraw + 64;    // 512 floats
        const int q = bx - 64;
        const int b = q / 12, jq = q - b * 12;
        const float* hvec;
        const float* Wbase;
        if (jq < 4) { hvec = str + b * STR_D + jq * 64;         Wbase = Wstr + (size_t)(jq * 64) * ATTN_D; }
        else        { hvec = cell + b * CELL_D + (jq - 4) * 64; Wbase = Wcell + (size_t)((jq - 4) * 64) * ATTN_D; }
        if (t < 64) sj[t] = hvec[t];
        __syncthreads();
        const int h = t >> 7, a4 = t & 127;
        f32x4 acc = {0.f, 0.f, 0.f, 0.f};
#pragma unroll 8
        for (int i = h * 32; i < h * 32 + 32; ++i) {
            const float s = sj[i];
            const float4 wv = *(const float4*)(Wbase + (size_t)i * ATTN_D + a4 * 4);
            acc[0] += s * wv.x; acc[1] += s * wv.y; acc[2] += s * wv.z; acc[3] += s * wv.w;
        }
        if (h == 1) *(f32x4*)(red + a4 * 4) = acc;
        __syncthreads();
        if (h == 0) {
            const f32x4 o = *(const f32x4*)(red + a4 * 4);
            acc[0] += o[0]; acc[1] += o[1]; acc[2] += o[2]; acc[3] += o[3];
            *(f32x4*)(bpart + (size_t)(jq * BATCH + b) * ATTN_D + a4 * 4) = acc;
        }
    }
}

// ---------------------------------------------------------------------------
// Kernel 2 (K-OUTER restructure): 512 blocks x 512 threads, M=128 rows/block,
// all 512 N-cols space-partitioned across 8 waves (2M x 4N grid: wave owns
// 64 rows x 128 cols, acc[4][8] f32x4 = 128 VGPRs). Outer loop = 16 K-slices
// (32-k, 32 KB WF slice each) through the same 3-deep ring + vmcnt(4) ledger.
// vs r0-lineage: (1) E-loads stream INSIDE the loop (8 loads+cvt/wave/chunk)
// so the 128 MB HBM read overlaps LDS+MFMA instead of preceding them;
// (2) each wave reads only ITS 8 n-tiles per slice -> B LDS traffic 4 MB/CU
// -> 1 MB/CU, MFMA:ds_read 2:1 -> 4:1; (3) bias/ReLU/Wcomb epilogue runs
// ONCE after the K loop, not per chunk. Ledger per chunk: issue A(8), issue
// stage ch+2 (4); compiler's own vmcnt(4) before A-use also proves stage(ch+1)
// landed (in-order vmcnt retirement); BAR_VM4 keeps stage(ch+2) in flight.
// launch_bounds(512,2): VGPR cap 256 for ~230 live (spill tripwire: VGPR=256
// + occupancy < 12%).
// ---------------------------------------------------------------------------
__global__ __launch_bounds__(512, 2) void k_scores(const float* __restrict__ E,
                                                   const unsigned short* __restrict__ WF,
                                                   const float* __restrict__ bpart,
                                                   const float* __restrict__ b_enc,
                                                   const float* __restrict__ b_str,
                                                   const float* __restrict__ b_cell,
                                                   const float* __restrict__ Wcomb,
                                                   float* __restrict__ ctxp,
                                                   float* __restrict__ stats) {
    __shared__ unsigned short buf[3][16384];    // 3 x 32 KB k-slices
    __shared__ float sbias[512];
    __shared__ float sWc[512];
    __shared__ float sxp[4][128];               // per-wn row-score partials
    __shared__ float sx[128];                   // final raw scores (block rows)
    __shared__ float ex[128];                   // e^(s - m_p)
    __shared__ float red[3][512];               // ctx 4->1 group reduce
    __shared__ float rtmp[4];

    const int tid = threadIdx.x;
    const int r0 = blockIdx.x * 128;
    const int b = blockIdx.x >> 3;              // 8 blocks per batch
    const int w = tid >> 6, lane = tid & 63;
    const int wm = w >> 2, wn = w & 3;          // 2M x 4N wave grid
    const int quad = lane >> 4, c = lane & 15;

    // stage k-slices 0 and 1 (async, 2 x 32 KB = 4 issues x 512 thr x 16 B)
#pragma unroll
    for (int p = 0; p < 2; ++p)
#pragma unroll
        for (int i = 0; i < 4; ++i)
            lds_cp16((char*)&buf[p][0] + i * 8192 + tid * 16,
                     (const char*)WF + (size_t)p * 32768 + i * 8192 + tid * 16);

    // bias finalize into LDS (overlaps staging)
    if (tid < 128) {
        const int a = tid * 4;
        const float4 be = *(const float4*)(b_enc + a);
        const float4 bs = *(const float4*)(b_str + a);
        const float4 bc = *(const float4*)(b_cell + a);
        f32x4 s;
        s[0] = be.x + bs.x + bc.x; s[1] = be.y + bs.y + bc.y;
        s[2] = be.z + bs.z + bc.z; s[3] = be.w + bs.w + bc.w;
#pragma unroll
        for (int jq = 0; jq < 12; ++jq) {
            const float4 p = *(const float4*)(bpart + (size_t)(jq * BATCH + b) * ATTN_D + a);
            s[0] += p.x; s[1] += p.y; s[2] += p.z; s[3] += p.w;
        }
        *(f32x4*)(sbias + a) = s;
        const float4 wcv = *(const float4*)(Wcomb + a);
        f32x4 wc4; wc4[0] = wcv.x; wc4[1] = wcv.y; wc4[2] = wcv.z; wc4[3] = wcv.w;
        *(f32x4*)(sWc + a) = wc4;
    }

    // accumulators: wave's 4 m-tiles x 8 n-tiles
    f32x4 acc[4][8];
#pragma unroll
    for (int mt = 0; mt < 4; ++mt)
#pragma unroll
        for (int nt = 0; nt < 8; ++nt) {
            const f32x4 z = {0.f, 0.f, 0.f, 0.f};
            acc[mt][nt] = z;
        }

    __syncthreads();   // full drain once: slices 0,1 staged; sbias/sWc visible

    const float* Ebase = E + (size_t)(r0 + wm * 64 + c) * ENC_D + quad * 8;

    int cbuf = 0, sbuf = 2;
    for (int ch = 0; ch < 16; ++ch) {
        // (1) issue A-loads for this k-slice: 4 m-tiles x 32 B contiguous
        float4 v0[4], v1[4];
#pragma unroll
        for (int mt = 0; mt < 4; ++mt) {
            const float* Ep = Ebase + (size_t)(mt * 16) * ENC_D + ch * 32;
            v0[mt] = *(const float4*)(Ep);
            v1[mt] = *(const float4*)(Ep + 4);
        }

        // (2) issue async staging for slice ch+2 into the free ring slot
        if (ch < 14) {
            const char* gsrc = (const char*)WF + (size_t)(ch + 2) * 32768;
            char* ldst = (char*)&buf[sbuf][0];
#pragma unroll
            for (int i = 0; i < 4; ++i)
                lds_cp16(ldst + i * 8192 + tid * 16, gsrc + i * 8192 + tid * 16);
        }

        // (3) convert A to bf16 fragments (compiler waits vmcnt(4) here,
        //     which also proves stage(ch+1) landed; stage(ch+2) stays in flight)
        bf16x8 av[4];
#pragma unroll
        for (int mt = 0; mt < 4; ++mt) {
            union { unsigned short s[8]; bf16x8 v; } u;
            u.s[0] = f2bf(v0[mt].x); u.s[1] = f2bf(v0[mt].y);
            u.s[2] = f2bf(v0[mt].z); u.s[3] = f2bf(v0[mt].w);
            u.s[4] = f2bf(v1[mt].x); u.s[5] = f2bf(v1[mt].y);
            u.s[6] = f2bf(v1[mt].z); u.s[7] = f2bf(v1[mt].w);
            av[mt] = u.v;
        }

        // (4) B fragments for this wave's 8 n-tiles, then 32 MFMAs
        const unsigned short* wb = &buf[cbuf][0];
        bf16x8 bfr[8];
#pragma unroll
        for (int nt = 0; nt < 8; ++nt)
            bfr[nt] = *(const bf16x8*)(wb + ((wn * 8 + nt) * 64 + lane) * 8);
#pragma unroll
        for (int nt = 0; nt < 8; ++nt)
#pragma unroll
            for (int mt = 0; mt < 4; ++mt)
                acc[mt][nt] = __builtin_amdgcn_mfma_f32_16x16x32_bf16(av[mt], bfr[nt], acc[mt][nt], 0, 0, 0);

        // rotate ring; fenced barrier keeping the newest prefetch in flight
        cbuf = (cbuf == 2) ? 0 : cbuf + 1;
        sbuf = (sbuf == 2) ? 0 : sbuf + 1;
        if (ch < 15) BAR_VM4();
    }

    // ---- epilogue (once): bias + relu + dot(W_comb) over the wave's tile ----
    // D-frag: row = mt*16 + quad*4 + reg, col = wn*128 + nt*16 + c
    float sp[4][4];
#pragma unroll
    for (int mt = 0; mt < 4; ++mt)
#pragma unroll
        for (int reg = 0; reg < 4; ++reg) sp[mt][reg] = 0.f;
#pragma unroll
    for (int nt = 0; nt < 8; ++nt) {
        const int col = wn * 128 + nt * 16 + c;
        const float bi = sbias[col], wc = sWc[col];
#pragma unroll
        for (int mt = 0; mt < 4; ++mt)
#pragma unroll
            for (int reg = 0; reg < 4; ++reg) {
                const float v = acc[mt][nt][reg] + bi;
                sp[mt][reg] += (v > 0.f ? v : 0.f) * wc;
            }
    }
    // reduce over the 16 c-lanes (same rows, different cols)
#pragma unroll
    for (int mt = 0; mt < 4; ++mt)
#pragma unroll
        for (int reg = 0; reg < 4; ++reg) {
            float v = sp[mt][reg];
            v += __shfl_xor(v, 1);
            v += __shfl_xor(v, 2);
            v += __shfl_xor(v, 4);
            v += __shfl_xor(v, 8);
            sp[mt][reg] = v;
        }
    if (c == 0) {
#pragma unroll
        for (int mt = 0; mt < 4; ++mt)
#pragma unroll
            for (int reg = 0; reg < 4; ++reg)
                sxp[wn][wm * 64 + mt * 16 + quad * 4 + reg] = sp[mt][reg];
    }
    __syncthreads();

    // combine the 4 wn-partials -> raw scores sx[128]
    if (tid < 128)
        sx[tid] = sxp[0][tid] + sxp[1][tid] + sxp[2][tid] + sxp[3][tid];
    // (same threads read their own write below; cross-thread use is after sync)

    // ---- block-local softmax partial over the 128 rows (waves 0,1) ----
    if (tid < 128) {
        float mm = sx[tid];
#pragma unroll
        for (int o = 32; o > 0; o >>= 1) mm = fmaxf(mm, __shfl_xor(mm, o));
        if (lane == 0) rtmp[w] = mm;
    }
    __syncthreads();
    const float m_p = fmaxf(rtmp[0], rtmp[1]);
    if (tid < 128) {
        const float e = __expf(sx[tid] - m_p);
        ex[tid] = e;
        float ss = e;
#pragma unroll
        for (int o = 32; o > 0; o >>= 1) ss += __shfl_xor(ss, o);
        if (lane == 0) rtmp[2 + w] = ss;
    }
    __syncthreads();   // publishes ex[] and partial sums
    if (tid == 0) {
        stats[blockIdx.x * 2 + 0] = m_p;
        stats[blockIdx.x * 2 + 1] = rtmp[2] + rtmp[3];
    }

    // ---- partial context: ctx_p[512] = sum_l ex[l] * E[r0+l, :] ----
    // 4 row-groups of 32 x 128 col4-threads; E slice re-read f32 (L3-hot).
    {
        const int g = tid >> 7, col4 = tid & 127;
        const float* Ep = E + (size_t)(r0 + g * 32) * ENC_D + col4 * 4;
        f32x4 a4 = {0.f, 0.f, 0.f, 0.f};
#pragma unroll 8
        for (int l = 0; l < 32; ++l) {
            const float4 e4 = *(const float4*)(Ep + (size_t)l * ENC_D);
            const float wgt = ex[g * 32 + l];
            a4[0] += wgt * e4.x; a4[1] += wgt * e4.y;
            a4[2] += wgt * e4.z; a4[3] += wgt * e4.w;
        }
        if (g > 0) *(f32x4*)(&red[g - 1][col4 * 4]) = a4;
        __syncthreads();
        if (g == 0) {
            const f32x4 r1 = *(const f32x4*)(&red[0][col4 * 4]);
            const f32x4 r2 = *(const f32x4*)(&red[1][col4 * 4]);
            const f32x4 r3 = *(const f32x4*)(&red[2][col4 * 4]);
            a4[0] += r1[0] + r2[0] + r3[0];
            a4[1] += r1[1] + r2[1] + r3[1];
            a4[2] += r1[2] + r2[2] + r3[2];
            a4[3] += r1[3] + r2[3] + r3[3];
            *(f32x4*)(ctxp + (size_t)blockIdx.x * 512 + col4 * 4) = a4;
        }
    }
}

// ---------------------------------------------------------------------------
// Kernel 3: combine the 8 per-batch partials with max-rescaling.
// out[b,:] = sum_p ctx_p * e^(m_p - m) / sum_p Z_p * e^(m_p - m).
// 64 blocks x 128 threads, ~1 MB read, trivial.
// ---------------------------------------------------------------------------
__global__ __launch_bounds__(128) void k_final(const float* __restrict__ ctxp,
                                               const float* __restrict__ stats,
                                               float* __restrict__ out) {
    const int b = blockIdx.x, t = threadIdx.x;
    float mp[8], zp[8];
    float m = -1e30f;
#pragma unroll
    for (int p = 0; p < 8; ++p) {
        mp[p] = stats[(b * 8 + p) * 2];
        zp[p] = stats[(b * 8 + p) * 2 + 1];
        m = fmaxf(m, mp[p]);
    }
    float D = 0.f;
    float a[8];
#pragma unroll
    for (int p = 0; p < 8; ++p) { a[p] = __expf(mp[p] - m); D += zp[p] * a[p]; }
    const float invD = 1.f / D;

    f32x4 o = {0.f, 0.f, 0.f, 0.f};
#pragma unroll
    for (int p = 0; p < 8; ++p) {
        const float4 cp = *(const float4*)(ctxp + (size_t)(b * 8 + p) * 512 + t * 4);
        o[0] += cp.x * a[p]; o[1] += cp.y * a[p];
        o[2] += cp.z * a[p]; o[3] += cp.w * a[p];
    }
    o[0] *= invD; o[1] *= invD; o[2] *= invD; o[3] *= invD;
    *(f32x4*)(out + (size_t)b * ENC_D + t * 4) = o;
}

// ---------------------------------------------------------------------------
extern "C" void kernel_launch(void* const* d_in, const int* in_sizes, int n_in,
                              void* d_out, int out_size, void* d_ws, size_t ws_size,
                              hipStream_t stream) {
    const float* E      = (const float*)d_in[0];
    const float* str    = (const float*)d_in[1];
    const float* cell   = (const float*)d_in[2];
    const float* Wenc   = (const float*)d_in[3];
    const float* b_enc  = (const float*)d_in[4];
    const float* Wstr   = (const float*)d_in[5];
    const float* b_str  = (const float*)d_in[6];
    const float* Wcell  = (const float*)d_in[7];
    const float* b_cell = (const float*)d_in[8];
    const float* Wcomb  = (const float*)d_in[9];
    // d_in[10] = b_comb: uniform pre-softmax shift — no effect, skipped.
    float* out = (float*)d_out;

    char* ws = (char*)d_ws;
    unsigned short* WF = (unsigned short*)ws;                  // 512 KB (k-slice-major)
    float* bpart = (float*)(ws + (512 << 10));                 // 1.5 MB
    float* ctxp  = (float*)(ws + (512 << 10) + (1536 << 10));  // 1 MB (512 blk x 512)
    float* stats = (float*)(ws + (512 << 10) + (2560 << 10));  // 4 KB

    k_prep<<<832, 256, 0, stream>>>(Wenc, WF, str, cell, Wstr, Wcell, bpart);
    k_scores<<<NROWS / 128, 512, 0, stream>>>(E, WF, bpart, b_enc, b_str, b_cell, Wcomb, ctxp, stats);
    k_final<<<BATCH, 128, 0, stream>>>(ctxp, stats, out);
}

// Round 5
// 284.344 us; speedup vs baseline: 1.0070x; 1.0070x over previous
//
#include <hip/hip_runtime.h>
#include <stdint.h>

#define ENC_D 512
#define ATTN_D 512
#define STR_D 256
#define CELL_D 512
#define BATCH 64
#define SEQ 1024
#define NROWS (BATCH * SEQ)

typedef __bf16 bf16x8 __attribute__((ext_vector_type(8)));
typedef float f32x4 __attribute__((ext_vector_type(4)));

__device__ __forceinline__ unsigned short f2bf(float f) {
    unsigned int u = __float_as_uint(f);
    u += 0x7fffu + ((u >> 16) & 1u);   // RNE
    return (unsigned short)(u >> 16);
}

// native-cast bf16x8 pack: compiler emits v_cvt_pk_bf16_f32 (RNE, identical
// numerics to f2bf) at ~1/4 the VALU cost of the manual bit-twiddle.
__device__ __forceinline__ bf16x8 cvt8(const float4 a, const float4 b) {
    bf16x8 r;
    r[0] = (__bf16)a.x; r[1] = (__bf16)a.y; r[2] = (__bf16)a.z; r[3] = (__bf16)a.w;
    r[4] = (__bf16)b.x; r[5] = (__bf16)b.y; r[6] = (__bf16)b.z; r[7] = (__bf16)b.w;
    return r;
}

__device__ __forceinline__ void lds_cp16(void* l, const void* g) {
    __builtin_amdgcn_global_load_lds(
        (const __attribute__((address_space(1))) unsigned int*)g,
        (__attribute__((address_space(3))) unsigned int*)l, 16, 0, 0);
}

// Plain barrier with compiler memory fence. NO waitcnt: the ledger (see
// k_scores header) proves each wave's stage(ch+1) retired at its own cvt
// wait (vmcnt(12)) BEFORE reaching this barrier, so no drain is needed and
// the 8 A-prefetch loads + 4 newest stage loads stay in flight across it.
#define BAR() asm volatile("s_barrier" ::: "memory")

// ---------------------------------------------------------------------------
// Kernel 1 (fused): blocks 0..63   : WF = bf16(W_enc^T) fragment-linear,
//                                    K-SLICE-MAJOR: gi = ks*2048 + nt*64
//                                    + quad*16 + c  (32 KB contiguous/slice)
//                   blocks 64..831 : bias partials [jq][b][a] (12 slabs)
// ---------------------------------------------------------------------------
__global__ __launch_bounds__(256) void k_prep(const float* __restrict__ W,
                                              unsigned short* __restrict__ WF,
                                              const float* __restrict__ str,
                                              const float* __restrict__ cell,
                                              const float* __restrict__ Wstr,
                                              const float* __restrict__ Wcell,
                                              float* __restrict__ bpart) {
    __shared__ char smraw[64 * 68 * 2];        // 8704 B, reused per role
    const int bx = blockIdx.x, t = threadIdx.x;

    if (bx < 64) {
        unsigned short* T = (unsigned short*)smraw;   // [n_local][e_local] stride 68
        const int ei = bx >> 3, ni = bx & 7;
        const int e0 = ei * 64, n0 = ni * 64;
#pragma unroll
        for (int i = 0; i < 4; ++i) {
            const int idx = t + i * 256;
            const int r = idx >> 4, c4 = idx & 15;
            const float4 v = *(const float4*)(W + (size_t)(e0 + r) * ATTN_D + n0 + c4 * 4);
            T[(c4 * 4 + 0) * 68 + r] = f2bf(v.x);
            T[(c4 * 4 + 1) * 68 + r] = f2bf(v.y);
            T[(c4 * 4 + 2) * 68 + r] = f2bf(v.z);
            T[(c4 * 4 + 3) * 68 + r] = f2bf(v.w);
        }
        __syncthreads();
#pragma unroll
        for (int i = 0; i < 2; ++i) {
            const int q = t + i * 256;
            const int n = q >> 3, ge = q & 7;
            union { unsigned short s[8]; uint4 u; } o;
#pragma unroll
            for (int j = 0; j < 8; ++j) o.s[j] = T[n * 68 + ge * 8 + j];
            const int ng = n0 + n;
            const int g = ei * 8 + ge;
            const int nt = ng >> 4, c = ng & 15;
            const int ks = g >> 2, quad = g & 3;
            const int gi = ks * 2048 + nt * 64 + quad * 16 + c;   // k-slice-major
            *(uint4*)(WF + (size_t)gi * 8) = o.u;
        }
    } else {
        float* sj = (float*)smraw;          // 64 floats
        float* red = (float*)smraw + 64;    // 512 floats
        const int q = bx - 64;
        const int b = q / 12, jq = q - b * 12;
        const float* hvec;
        const float* Wbase;
        if (jq < 4) { hvec = str + b * STR_D + jq * 64;         Wbase = Wstr + (size_t)(jq * 64) * ATTN_D; }
        else        { hvec = cell + b * CELL_D + (jq - 4) * 64; Wbase = Wcell + (size_t)((jq - 4) * 64) * ATTN_D; }
        if (t < 64) sj[t] = hvec[t];
        __syncthreads();
        const int h = t >> 7, a4 = t & 127;
        f32x4 acc = {0.f, 0.f, 0.f, 0.f};
#pragma unroll 8
        for (int i = h * 32; i < h * 32 + 32; ++i) {
            const float s = sj[i];
            const float4 wv = *(const float4*)(Wbase + (size_t)i * ATTN_D + a4 * 4);
            acc[0] += s * wv.x; acc[1] += s * wv.y; acc[2] += s * wv.z; acc[3] += s * wv.w;
        }
        if (h == 1) *(f32x4*)(red + a4 * 4) = acc;
        __syncthreads();
        if (h == 0) {
            const f32x4 o = *(const f32x4*)(red + a4 * 4);
            acc[0] += o[0]; acc[1] += o[1]; acc[2] += o[2]; acc[3] += o[3];
            *(f32x4*)(bpart + (size_t)(jq * BATCH + b) * ATTN_D + a4 * 4) = acc;
        }
    }
}

// ---------------------------------------------------------------------------
// Kernel 2 (K-outer, pipeline-fixed). 512 blocks x 512 threads, M=128/block,
// wave grid 2M x 4N (wave = 64 rows x 128 cols, acc[4][8]). r4's regression
// root-caused: (a) the CONDITIONAL `if(ch<14)` staging made the compiler's
// A-load wait un-analyzable -> it emitted vmcnt(0) per chunk, full-draining
// the pipeline; (b) A-loads were used ~10 instrs after issue (full latency
// exposed); (c) manual f2bf cvt = 4x the needed VALU.
// Fixes: branch-free steady-state body (peel ch=14,15) so all counts are
// static; A-prefetch ONE CHUNK ahead via explicit ping-pong reg sets in a
// 2x-unrolled loop; native (__bf16) casts (v_cvt_pk_bf16_f32, same RNE).
// Ledger per iter ch (order: stage(ch+2)[4], A(ch+1)[8], cvt-A(ch), ds_read
// B(ch), MFMA, BAR): cvt waits A(ch) -> vmcnt(12) [A(ch) precedes
// stage(ch+2)+A(ch+1)]; since stage(ch+1) was issued BEFORE A(ch) (iter ch-1
// step 1 vs step 2), in-order retirement proves stage(ch+1) landed at that
// same wait -> the end-of-iter BAR needs NO vmcnt: 12 loads stay in flight
// across every barrier. ds_read B(ch) is safe: stage(ch) proven by iter
// ch-1's cvt wait + barrier.
// ---------------------------------------------------------------------------
#define CHUNK(ch, CUR0, CUR1, NXT0, NXT1, DO_STAGE, DO_PREF, DO_BAR)               \
    do {                                                                           \
        if (DO_STAGE) {                                                            \
            const char* gsrc = (const char*)WF + (size_t)((ch) + 2) * 32768;       \
            char* ldst = (char*)&buf[sbuf][0];                                     \
            _Pragma("unroll")                                                      \
            for (int i = 0; i < 4; ++i)                                            \
                lds_cp16(ldst + i * 8192 + tid * 16, gsrc + i * 8192 + tid * 16);  \
        }                                                                          \
        if (DO_PREF) {                                                             \
            _Pragma("unroll")                                                      \
            for (int mt = 0; mt < 4; ++mt) {                                       \
                const float* Ep = Ebase + (size_t)(mt * 16) * ENC_D + ((ch) + 1) * 32; \
                NXT0[mt] = *(const float4*)(Ep);                                   \
                NXT1[mt] = *(const float4*)(Ep + 4);                               \
            }                                                                      \
        }                                                                          \
        bf16x8 av[4];                                                              \
        _Pragma("unroll")                                                          \
        for (int mt = 0; mt < 4; ++mt) av[mt] = cvt8(CUR0[mt], CUR1[mt]);          \
        const unsigned short* wb = &buf[cbuf][0];                                  \
        _Pragma("unroll")                                                          \
        for (int nt = 0; nt < 8; ++nt) {                                           \
            const bf16x8 bfr = *(const bf16x8*)(wb + ((wn * 8 + nt) * 64 + lane) * 8); \
            _Pragma("unroll")                                                      \
            for (int mt = 0; mt < 4; ++mt)                                         \
                acc[mt][nt] = __builtin_amdgcn_mfma_f32_16x16x32_bf16(av[mt], bfr, \
                                                        acc[mt][nt], 0, 0, 0);     \
        }                                                                          \
        cbuf = (cbuf == 2) ? 0 : cbuf + 1;                                         \
        sbuf = (sbuf == 2) ? 0 : sbuf + 1;                                         \
        if (DO_BAR) BAR();                                                         \
    } while (0)

__global__ __launch_bounds__(512, 2) void k_scores(const float* __restrict__ E,
                                                   const unsigned short* __restrict__ WF,
                                                   const float* __restrict__ bpart,
                                                   const float* __restrict__ b_enc,
                                                   const float* __restrict__ b_str,
                                                   const float* __restrict__ b_cell,
                                                   const float* __restrict__ Wcomb,
                                                   float* __restrict__ ctxp,
                                                   float* __restrict__ stats) {
    __shared__ unsigned short buf[3][16384];    // 3 x 32 KB k-slices
    __shared__ float sbias[512];
    __shared__ float sWc[512];
    __shared__ float sxp[4][128];               // per-wn row-score partials
    __shared__ float sx[128];                   // final raw scores (block rows)
    __shared__ float ex[128];                   // e^(s - m_p)
    __shared__ float red[3][512];               // ctx 4->1 group reduce
    __shared__ float rtmp[4];

    const int tid = threadIdx.x;
    const int r0 = blockIdx.x * 128;
    const int b = blockIdx.x >> 3;              // 8 blocks per batch
    const int w = tid >> 6, lane = tid & 63;
    const int wm = w >> 2, wn = w & 3;          // 2M x 4N wave grid
    const int quad = lane >> 4, c = lane & 15;

    // stage k-slices 0 and 1 (async, 2 x 32 KB = 4 issues x 512 thr x 16 B)
#pragma unroll
    for (int p = 0; p < 2; ++p)
#pragma unroll
        for (int i = 0; i < 4; ++i)
            lds_cp16((char*)&buf[p][0] + i * 8192 + tid * 16,
                     (const char*)WF + (size_t)p * 32768 + i * 8192 + tid * 16);

    // bias finalize into LDS (overlaps staging)
    if (tid < 128) {
        const int a = tid * 4;
        const float4 be = *(const float4*)(b_enc + a);
        const float4 bs = *(const float4*)(b_str + a);
        const float4 bc = *(const float4*)(b_cell + a);
        f32x4 s;
        s[0] = be.x + bs.x + bc.x; s[1] = be.y + bs.y + bc.y;
        s[2] = be.z + bs.z + bc.z; s[3] = be.w + bs.w + bc.w;
#pragma unroll
        for (int jq = 0; jq < 12; ++jq) {
            const float4 p = *(const float4*)(bpart + (size_t)(jq * BATCH + b) * ATTN_D + a);
            s[0] += p.x; s[1] += p.y; s[2] += p.z; s[3] += p.w;
        }
        *(f32x4*)(sbias + a) = s;
        const float4 wcv = *(const float4*)(Wcomb + a);
        f32x4 wc4; wc4[0] = wcv.x; wc4[1] = wcv.y; wc4[2] = wcv.z; wc4[3] = wcv.w;
        *(f32x4*)(sWc + a) = wc4;
    }

    // accumulators: wave's 4 m-tiles x 8 n-tiles
    f32x4 acc[4][8];
#pragma unroll
    for (int mt = 0; mt < 4; ++mt)
#pragma unroll
        for (int nt = 0; nt < 8; ++nt) {
            const f32x4 z = {0.f, 0.f, 0.f, 0.f};
            acc[mt][nt] = z;
        }

    const float* Ebase = E + (size_t)(r0 + wm * 64 + c) * ENC_D + quad * 8;

    // A(0) into the ping set (drained by the prologue __syncthreads — fine,
    // this is the one full drain of the kernel)
    float4 pA0[4], pA1[4], pB0[4], pB1[4];
#pragma unroll
    for (int mt = 0; mt < 4; ++mt) {
        const float* Ep = Ebase + (size_t)(mt * 16) * ENC_D;
        pA0[mt] = *(const float4*)(Ep);
        pA1[mt] = *(const float4*)(Ep + 4);
    }

    __syncthreads();   // slices 0,1 staged; sbias/sWc visible; A(0) in regs

    int cbuf = 0, sbuf = 2;
    // steady state: chunks 0..13, branch-free bodies, 2x-unrolled ping-pong
    for (int cc = 0; cc < 14; cc += 2) {
        CHUNK(cc,     pA0, pA1, pB0, pB1, true, true, true);
        CHUNK(cc + 1, pB0, pB1, pA0, pA1, true, true, true);
    }
    // peeled tail: ch=14 (prefetch only), ch=15 (compute only, no barrier)
    CHUNK(14, pA0, pA1, pB0, pB1, false, true, true);
    CHUNK(15, pB0, pB1, pA0, pA1, false, false, false);

    // ---- epilogue (once): bias + relu + dot(W_comb) over the wave's tile ----
    // D-frag: row = mt*16 + quad*4 + reg, col = wn*128 + nt*16 + c
    float sp[4][4];
#pragma unroll
    for (int mt = 0; mt < 4; ++mt)
#pragma unroll
        for (int reg = 0; reg < 4; ++reg) sp[mt][reg] = 0.f;
#pragma unroll
    for (int nt = 0; nt < 8; ++nt) {
        const int col = wn * 128 + nt * 16 + c;
        const float bi = sbias[col], wc = sWc[col];
#pragma unroll
        for (int mt = 0; mt < 4; ++mt)
#pragma unroll
            for (int reg = 0; reg < 4; ++reg) {
                const float v = acc[mt][nt][reg] + bi;
                sp[mt][reg] += (v > 0.f ? v : 0.f) * wc;
            }
    }
    // reduce over the 16 c-lanes (same rows, different cols)
#pragma unroll
    for (int mt = 0; mt < 4; ++mt)
#pragma unroll
        for (int reg = 0; reg < 4; ++reg) {
            float v = sp[mt][reg];
            v += __shfl_xor(v, 1);
            v += __shfl_xor(v, 2);
            v += __shfl_xor(v, 4);
            v += __shfl_xor(v, 8);
            sp[mt][reg] = v;
        }
    if (c == 0) {
#pragma unroll
        for (int mt = 0; mt < 4; ++mt)
#pragma unroll
            for (int reg = 0; reg < 4; ++reg)
                sxp[wn][wm * 64 + mt * 16 + quad * 4 + reg] = sp[mt][reg];
    }
    __syncthreads();

    // combine the 4 wn-partials -> raw scores sx[128]
    if (tid < 128)
        sx[tid] = sxp[0][tid] + sxp[1][tid] + sxp[2][tid] + sxp[3][tid];

    // ---- block-local softmax partial over the 128 rows (waves 0,1) ----
    if (tid < 128) {
        float mm = sx[tid];
#pragma unroll
        for (int o = 32; o > 0; o >>= 1) mm = fmaxf(mm, __shfl_xor(mm, o));
        if (lane == 0) rtmp[w] = mm;
    }
    __syncthreads();
    const float m_p = fmaxf(rtmp[0], rtmp[1]);
    if (tid < 128) {
        const float e = __expf(sx[tid] - m_p);
        ex[tid] = e;
        float ss = e;
#pragma unroll
        for (int o = 32; o > 0; o >>= 1) ss += __shfl_xor(ss, o);
        if (lane == 0) rtmp[2 + w] = ss;
    }
    __syncthreads();   // publishes ex[] and partial sums
    if (tid == 0) {
        stats[blockIdx.x * 2 + 0] = m_p;
        stats[blockIdx.x * 2 + 1] = rtmp[2] + rtmp[3];
    }

    // ---- partial context: ctx_p[512] = sum_l ex[l] * E[r0+l, :] ----
    // 4 row-groups of 32 x 128 col4-threads; E slice re-read f32 (L3-hot).
    {
        const int g = tid >> 7, col4 = tid & 127;
        const float* Ep = E + (size_t)(r0 + g * 32) * ENC_D + col4 * 4;
        f32x4 a4 = {0.f, 0.f, 0.f, 0.f};
#pragma unroll 8
        for (int l = 0; l < 32; ++l) {
            const float4 e4 = *(const float4*)(Ep + (size_t)l * ENC_D);
            const float wgt = ex[g * 32 + l];
            a4[0] += wgt * e4.x; a4[1] += wgt * e4.y;
            a4[2] += wgt * e4.z; a4[3] += wgt * e4.w;
        }
        if (g > 0) *(f32x4*)(&red[g - 1][col4 * 4]) = a4;
        __syncthreads();
        if (g == 0) {
            const f32x4 r1 = *(const f32x4*)(&red[0][col4 * 4]);
            const f32x4 r2 = *(const f32x4*)(&red[1][col4 * 4]);
            const f32x4 r3 = *(const f32x4*)(&red[2][col4 * 4]);
            a4[0] += r1[0] + r2[0] + r3[0];
            a4[1] += r1[1] + r2[1] + r3[1];
            a4[2] += r1[2] + r2[2] + r3[2];
            a4[3] += r1[3] + r2[3] + r3[3];
            *(f32x4*)(ctxp + (size_t)blockIdx.x * 512 + col4 * 4) = a4;
        }
    }
}

// ---------------------------------------------------------------------------
// Kernel 3: combine the 8 per-batch partials with max-rescaling.
// out[b,:] = sum_p ctx_p * e^(m_p - m) / sum_p Z_p * e^(m_p - m).
// 64 blocks x 128 threads, ~1 MB read, trivial.
// ---------------------------------------------------------------------------
__global__ __launch_bounds__(128) void k_final(const float* __restrict__ ctxp,
                                               const float* __restrict__ stats,
                                               float* __restrict__ out) {
    const int b = blockIdx.x, t = threadIdx.x;
    float mp[8], zp[8];
    float m = -1e30f;
#pragma unroll
    for (int p = 0; p < 8; ++p) {
        mp[p] = stats[(b * 8 + p) * 2];
        zp[p] = stats[(b * 8 + p) * 2 + 1];
        m = fmaxf(m, mp[p]);
    }
    float D = 0.f;
    float a[8];
#pragma unroll
    for (int p = 0; p < 8; ++p) { a[p] = __expf(mp[p] - m); D += zp[p] * a[p]; }
    const float invD = 1.f / D;

    f32x4 o = {0.f, 0.f, 0.f, 0.f};
#pragma unroll
    for (int p = 0; p < 8; ++p) {
        const float4 cp = *(const float4*)(ctxp + (size_t)(b * 8 + p) * 512 + t * 4);
        o[0] += cp.x * a[p]; o[1] += cp.y * a[p];
        o[2] += cp.z * a[p]; o[3] += cp.w * a[p];
    }
    o[0] *= invD; o[1] *= invD; o[2] *= invD; o[3] *= invD;
    *(f32x4*)(out + (size_t)b * ENC_D + t * 4) = o;
}

// ---------------------------------------------------------------------------
extern "C" void kernel_launch(void* const* d_in, const int* in_sizes, int n_in,
                              void* d_out, int out_size, void* d_ws, size_t ws_size,
                              hipStream_t stream) {
    const float* E      = (const float*)d_in[0];
    const float* str    = (const float*)d_in[1];
    const float* cell   = (const float*)d_in[2];
    const float* Wenc   = (const float*)d_in[3];
    const float* b_enc  = (const float*)d_in[4];
    const float* Wstr   = (const float*)d_in[5];
    const float* b_str  = (const float*)d_in[6];
    const float* Wcell  = (const float*)d_in[7];
    const float* b_cell = (const float*)d_in[8];
    const float* Wcomb  = (const float*)d_in[9];
    // d_in[10] = b_comb: uniform pre-softmax shift — no effect, skipped.
    float* out = (float*)d_out;

    char* ws = (char*)d_ws;
    unsigned short* WF = (unsigned short*)ws;                  // 512 KB (k-slice-major)
    float* bpart = (float*)(ws + (512 << 10));                 // 1.5 MB
    float* ctxp  = (float*)(ws + (512 << 10) + (1536 << 10));  // 1 MB (512 blk x 512)
    float* stats = (float*)(ws + (512 << 10) + (2560 << 10));  // 4 KB

    k_prep<<<832, 256, 0, stream>>>(Wenc, WF, str, cell, Wstr, Wcell, bpart);
    k_scores<<<NROWS / 128, 512, 0, stream>>>(E, WF, bpart, b_enc, b_str, b_cell, Wcomb, ctxp, stats);
    k_final<<<BATCH, 128, 0, stream>>>(ctxp, stats, out);
}

// Round 6
// 262.845 us; speedup vs baseline: 1.0893x; 1.0818x over previous
//
#include <hip/hip_runtime.h>
#include <stdint.h>

#define ENC_D 512
#define ATTN_D 512
#define STR_D 256
#define CELL_D 512
#define BATCH 64
#define SEQ 1024
#define NROWS (BATCH * SEQ)

typedef __bf16 bf16x8 __attribute__((ext_vector_type(8)));
typedef float f32x4 __attribute__((ext_vector_type(4)));

__device__ __forceinline__ unsigned short f2bf(float f) {
    unsigned int u = __float_as_uint(f);
    u += 0x7fffu + ((u >> 16) & 1u);   // RNE
    return (unsigned short)(u >> 16);
}

// native-cast bf16x8 pack: compiler emits v_cvt_pk_bf16_f32 (RNE, identical
// numerics to f2bf — verified r5: absmax unchanged) at ~1/4 the VALU cost.
__device__ __forceinline__ bf16x8 cvt8(const float4 a, const float4 b) {
    bf16x8 r;
    r[0] = (__bf16)a.x; r[1] = (__bf16)a.y; r[2] = (__bf16)a.z; r[3] = (__bf16)a.w;
    r[4] = (__bf16)b.x; r[5] = (__bf16)b.y; r[6] = (__bf16)b.z; r[7] = (__bf16)b.w;
    return r;
}

__device__ __forceinline__ void lds_cp16(void* l, const void* g) {
    __builtin_amdgcn_global_load_lds(
        (const __attribute__((address_space(1))) unsigned int*)g,
        (__attribute__((address_space(3))) unsigned int*)l, 16, 0, 0);
}

// Fused waitcnt+barrier as ONE asm with a memory clobber: the clobber is the
// compiler fence (bare builtins are not), the vmcnt(N) leaves the newest
// prefetch in flight across the barrier (no full drain).
#define BAR_VM4() asm volatile("s_waitcnt vmcnt(4)\n\ts_barrier" ::: "memory")
#define BAR_VM0() asm volatile("s_waitcnt vmcnt(0)\n\ts_barrier" ::: "memory")

// ---------------------------------------------------------------------------
// Kernel 1 (fused): blocks 0..63   : WF = bf16(W_enc^T) fragment-linear
//                   blocks 64..831 : bias partials [jq][b][a] (12 slabs)
// WF granule (16 B) = 8 k-elems of one column; gi = nt*1024 + ks*64 + quad*16 + c.
// ---------------------------------------------------------------------------
__global__ __launch_bounds__(256) void k_prep(const float* __restrict__ W,
                                              unsigned short* __restrict__ WF,
                                              const float* __restrict__ str,
                                              const float* __restrict__ cell,
                                              const float* __restrict__ Wstr,
                                              const float* __restrict__ Wcell,
                                              float* __restrict__ bpart) {
    __shared__ char smraw[64 * 68 * 2];        // 8704 B, reused per role
    const int bx = blockIdx.x, t = threadIdx.x;

    if (bx < 64) {
        unsigned short* T = (unsigned short*)smraw;   // [n_local][e_local] stride 68
        const int ei = bx >> 3, ni = bx & 7;
        const int e0 = ei * 64, n0 = ni * 64;
#pragma unroll
        for (int i = 0; i < 4; ++i) {
            const int idx = t + i * 256;
            const int r = idx >> 4, c4 = idx & 15;
            const float4 v = *(const float4*)(W + (size_t)(e0 + r) * ATTN_D + n0 + c4 * 4);
            T[(c4 * 4 + 0) * 68 + r] = f2bf(v.x);
            T[(c4 * 4 + 1) * 68 + r] = f2bf(v.y);
            T[(c4 * 4 + 2) * 68 + r] = f2bf(v.z);
            T[(c4 * 4 + 3) * 68 + r] = f2bf(v.w);
        }
        __syncthreads();
#pragma unroll
        for (int i = 0; i < 2; ++i) {
            const int q = t + i * 256;
            const int n = q >> 3, ge = q & 7;
            union { unsigned short s[8]; uint4 u; } o;
#pragma unroll
            for (int j = 0; j < 8; ++j) o.s[j] = T[n * 68 + ge * 8 + j];
            const int ng = n0 + n;
            const int g = ei * 8 + ge;
            const int nt = ng >> 4, c = ng & 15;
            const int ks = g >> 2, quad = g & 3;
            const int gi = nt * 1024 + ks * 64 + quad * 16 + c;
            *(uint4*)(WF + (size_t)gi * 8) = o.u;
        }
    } else {
        float* sj = (float*)smraw;          // 64 floats
        float* red = (float*)smraw + 64;    // 512 floats
        const int q = bx - 64;
        const int b = q / 12, jq = q - b * 12;
        const float* hvec;
        const float* Wbase;
        if (jq < 4) { hvec = str + b * STR_D + jq * 64;         Wbase = Wstr + (size_t)(jq * 64) * ATTN_D; }
        else        { hvec = cell + b * CELL_D + (jq - 4) * 64; Wbase = Wcell + (size_t)((jq - 4) * 64) * ATTN_D; }
        if (t < 64) sj[t] = hvec[t];
        __syncthreads();
        const int h = t >> 7, a4 = t & 127;
        f32x4 acc = {0.f, 0.f, 0.f, 0.f};
#pragma unroll 8
        for (int i = h * 32; i < h * 32 + 32; ++i) {
            const float s = sj[i];
            const float4 wv = *(const float4*)(Wbase + (size_t)i * ATTN_D + a4 * 4);
            acc[0] += s * wv.x; acc[1] += s * wv.y; acc[2] += s * wv.z; acc[3] += s * wv.w;
        }
        if (h == 1) *(f32x4*)(red + a4 * 4) = acc;
        __syncthreads();
        if (h == 0) {
            const f32x4 o = *(const f32x4*)(red + a4 * 4);
            acc[0] += o[0]; acc[1] += o[1]; acc[2] += o[2]; acc[3] += o[3];
            *(f32x4*)(bpart + (size_t)(jq * BATCH + b) * ATTN_D + a4 * 4) = acc;
        }
    }
}

// ---------------------------------------------------------------------------
// Kernel 2: fused scores GEMM + flash-style partial context (r3 structure —
// best measured total). 256 blocks x 512 threads (8 waves), M=256/block,
// M=32/wave, 1 block/CU, 16 chunks of 32 cols, 3-deep 32 KB staging ring,
// vmcnt(4) never-drain ledger. The K-outer restructure (r4/r5) measured
// WORSE (124-126 vs 111.6) — A-load HBM latency not coverable per-chunk.
// r6 micro-fixes to r3 (all targeting exposed latency, no structure change):
// (1) E-phase uses native cvt8 (v_cvt_pk_bf16_f32) instead of manual f2bf —
//     removes ~3/4 of the serial pack VALU from the ~25 us E-load phase;
// (2) inner loop batches 8 ds_read_b128 (ks unrolled x4) before 16 MFMAs —
//     halves the lgkm wait points per chunk (8 batches -> 4);
// (3) ctx epilogue: two independent accumulator chains (even/odd rows) —
//     halves the dependent-FMA chain stall of the tail.
// ---------------------------------------------------------------------------
__global__ __launch_bounds__(512, 1) void k_scores(const float* __restrict__ E,
                                                   const unsigned short* __restrict__ WF,
                                                   const float* __restrict__ bpart,
                                                   const float* __restrict__ b_enc,
                                                   const float* __restrict__ b_str,
                                                   const float* __restrict__ b_cell,
                                                   const float* __restrict__ Wcomb,
                                                   float* __restrict__ ctxp,
                                                   float* __restrict__ stats) {
    __shared__ unsigned short buf[3][16384];    // 3 x 32 KB
    __shared__ float sbias[512];
    __shared__ float sWc[512];
    __shared__ float sx[256];                   // raw scores of this block's rows
    __shared__ float ex[256];                   // e^(s - m_p)
    __shared__ float red[3][512];               // ctx 4->1 group reduce
    __shared__ float rtmp[8];

    const int tid = threadIdx.x;
    const int r0 = blockIdx.x * 256;
    const int b = blockIdx.x >> 2;              // 4 blocks per batch
    const int w = tid >> 6, lane = tid & 63;
    const int quad = lane >> 4, c = lane & 15;

    // stage chunks 0 and 1 (async, 2 x 32 KB = 4 issues x 512 thr x 16 B each)
#pragma unroll
    for (int p = 0; p < 2; ++p)
#pragma unroll
        for (int i = 0; i < 4; ++i)
            lds_cp16((char*)&buf[p][0] + i * 8192 + tid * 16,
                     (const char*)WF + (size_t)p * 32768 + i * 8192 + tid * 16);

    // bias finalize into LDS (overlaps staging)
    if (tid < 128) {
        const int a = tid * 4;
        const float4 be = *(const float4*)(b_enc + a);
        const float4 bs = *(const float4*)(b_str + a);
        const float4 bc = *(const float4*)(b_cell + a);
        f32x4 s;
        s[0] = be.x + bs.x + bc.x; s[1] = be.y + bs.y + bc.y;
        s[2] = be.z + bs.z + bc.z; s[3] = be.w + bs.w + bc.w;
#pragma unroll
        for (int jq = 0; jq < 12; ++jq) {
            const float4 p = *(const float4*)(bpart + (size_t)(jq * BATCH + b) * ATTN_D + a);
            s[0] += p.x; s[1] += p.y; s[2] += p.z; s[3] += p.w;
        }
        *(f32x4*)(sbias + a) = s;
        const float4 wcv = *(const float4*)(Wcomb + a);
        f32x4 wc4; wc4[0] = wcv.x; wc4[1] = wcv.y; wc4[2] = wcv.z; wc4[3] = wcv.w;
        *(f32x4*)(sWc + a) = wc4;
    }

    // load A: 2 M-tiles x full K in registers (E read exactly once here)
    bf16x8 afr[2][16];
#pragma unroll
    for (int m = 0; m < 2; ++m) {
        const float* Ep = E + (size_t)(r0 + w * 32 + m * 16 + c) * ENC_D + quad * 8;
#pragma unroll
        for (int ks = 0; ks < 16; ++ks) {
            const float4 v0 = *(const float4*)(Ep + ks * 32);
            const float4 v1 = *(const float4*)(Ep + ks * 32 + 4);
            afr[m][ks] = cvt8(v0, v1);
        }
    }

    float sc0[4] = {0.f, 0.f, 0.f, 0.f};
    float sc1[4] = {0.f, 0.f, 0.f, 0.f};

    __syncthreads();   // one full drain: chunks 0,1 staged; sbias/sWc visible

    int cbuf = 0, sbuf = 2;
    for (int ch = 0; ch < 16; ++ch) {
        // issue async staging for chunk ch+2 into the free ring slot
        if (ch < 14) {
            const char* gsrc = (const char*)WF + (size_t)(ch + 2) * 32768;
            char* ldst = (char*)&buf[sbuf][0];
#pragma unroll
            for (int i = 0; i < 4; ++i)
                lds_cp16(ldst + i * 8192 + tid * 16, gsrc + i * 8192 + tid * 16);
        }

        // compute chunk ch (8 independent accumulator chains)
        // buffer layout: nt0 granules at short-offset 0, nt1 at +8192 (16 KB)
        // ks unrolled x4: 8 ds_read_b128 issued per batch, then 16 MFMAs --
        // halves the number of lgkm wait points vs the 4-read batches of r3.
        const unsigned short* wb = &buf[cbuf][0];
        f32x4 a0e = {0.f,0.f,0.f,0.f}, a0o = {0.f,0.f,0.f,0.f};
        f32x4 a1e = {0.f,0.f,0.f,0.f}, a1o = {0.f,0.f,0.f,0.f};
        f32x4 b0e = {0.f,0.f,0.f,0.f}, b0o = {0.f,0.f,0.f,0.f};
        f32x4 b1e = {0.f,0.f,0.f,0.f}, b1o = {0.f,0.f,0.f,0.f};
#pragma unroll
        for (int ks = 0; ks < 16; ks += 4) {
            const bf16x8 f0 = *(const bf16x8*)(wb + ((ks + 0) * 64 + lane) * 8);
            const bf16x8 f1 = *(const bf16x8*)(wb + ((ks + 1) * 64 + lane) * 8);
            const bf16x8 f2 = *(const bf16x8*)(wb + ((ks + 2) * 64 + lane) * 8);
            const bf16x8 f3 = *(const bf16x8*)(wb + ((ks + 3) * 64 + lane) * 8);
            const bf16x8 g0 = *(const bf16x8*)(wb + 8192 + ((ks + 0) * 64 + lane) * 8);
            const bf16x8 g1 = *(const bf16x8*)(wb + 8192 + ((ks + 1) * 64 + lane) * 8);
            const bf16x8 g2 = *(const bf16x8*)(wb + 8192 + ((ks + 2) * 64 + lane) * 8);
            const bf16x8 g3 = *(const bf16x8*)(wb + 8192 + ((ks + 3) * 64 + lane) * 8);
            a0e = __builtin_amdgcn_mfma_f32_16x16x32_bf16(afr[0][ks + 0], f0, a0e, 0, 0, 0);
            a1e = __builtin_amdgcn_mfma_f32_16x16x32_bf16(afr[1][ks + 0], f0, a1e, 0, 0, 0);
            a0o = __builtin_amdgcn_mfma_f32_16x16x32_bf16(afr[0][ks + 1], f1, a0o, 0, 0, 0);
            a1o = __builtin_amdgcn_mfma_f32_16x16x32_bf16(afr[1][ks + 1], f1, a1o, 0, 0, 0);
            b0e = __builtin_amdgcn_mfma_f32_16x16x32_bf16(afr[0][ks + 0], g0, b0e, 0, 0, 0);
            b1e = __builtin_amdgcn_mfma_f32_16x16x32_bf16(afr[1][ks + 0], g0, b1e, 0, 0, 0);
            b0o = __builtin_amdgcn_mfma_f32_16x16x32_bf16(afr[0][ks + 1], g1, b0o, 0, 0, 0);
            b1o = __builtin_amdgcn_mfma_f32_16x16x32_bf16(afr[1][ks + 1], g1, b1o, 0, 0, 0);
            a0e = __builtin_amdgcn_mfma_f32_16x16x32_bf16(afr[0][ks + 2], f2, a0e, 0, 0, 0);
            a1e = __builtin_amdgcn_mfma_f32_16x16x32_bf16(afr[1][ks + 2], f2, a1e, 0, 0, 0);
            a0o = __builtin_amdgcn_mfma_f32_16x16x32_bf16(afr[0][ks + 3], f3, a0o, 0, 0, 0);
            a1o = __builtin_amdgcn_mfma_f32_16x16x32_bf16(afr[1][ks + 3], f3, a1o, 0, 0, 0);
            b0e = __builtin_amdgcn_mfma_f32_16x16x32_bf16(afr[0][ks + 2], g2, b0e, 0, 0, 0);
            b1e = __builtin_amdgcn_mfma_f32_16x16x32_bf16(afr[1][ks + 2], g2, b1e, 0, 0, 0);
            b0o = __builtin_amdgcn_mfma_f32_16x16x32_bf16(afr[0][ks + 3], g3, b0o, 0, 0, 0);
            b1o = __builtin_amdgcn_mfma_f32_16x16x32_bf16(afr[1][ks + 3], g3, b1o, 0, 0, 0);
        }

        // epilogue: bias + relu + dot(W_comb)
        const int n0 = ch * 32 + c;
        const float bi0 = sbias[n0], wc0 = sWc[n0];
        const float bi1 = sbias[n0 + 16], wc1 = sWc[n0 + 16];
#pragma unroll
        for (int r = 0; r < 4; ++r) {
            float v;
            v = (a0e[r] + a0o[r]) + bi0; sc0[r] += (v > 0.f ? v : 0.f) * wc0;
            v = (b0e[r] + b0o[r]) + bi1; sc0[r] += (v > 0.f ? v : 0.f) * wc1;
            v = (a1e[r] + a1o[r]) + bi0; sc1[r] += (v > 0.f ? v : 0.f) * wc0;
            v = (b1e[r] + b1o[r]) + bi1; sc1[r] += (v > 0.f ? v : 0.f) * wc1;
        }

        // rotate ring; fenced barrier keeping the newest prefetch in flight
        cbuf = (cbuf == 2) ? 0 : cbuf + 1;
        sbuf = (sbuf == 2) ? 0 : sbuf + 1;
        if (ch < 15) {
            if (ch < 14) BAR_VM4();
            else         BAR_VM0();
        }
    }

    // reduce across the 16 column-lanes; c==0 lanes hold the row scores
#pragma unroll
    for (int r = 0; r < 4; ++r) {
        float v0 = sc0[r], v1 = sc1[r];
        v0 += __shfl_xor(v0, 1); v1 += __shfl_xor(v1, 1);
        v0 += __shfl_xor(v0, 2); v1 += __shfl_xor(v1, 2);
        v0 += __shfl_xor(v0, 4); v1 += __shfl_xor(v1, 4);
        sc0[r] = v0 + __shfl_xor(v0, 8);
        sc1[r] = v1 + __shfl_xor(v1, 8);
    }
    if (c == 0) {
        const int l0 = w * 32 + quad * 4;
#pragma unroll
        for (int r = 0; r < 4; ++r) sx[l0 + r] = sc0[r];
#pragma unroll
        for (int r = 0; r < 4; ++r) sx[l0 + 16 + r] = sc1[r];
    }
    __syncthreads();

    // ---- block-local softmax partial over this block's 256 rows ----
    if (tid < 256) {
        float v = sx[tid];
        float mm = v;
#pragma unroll
        for (int o = 32; o > 0; o >>= 1) mm = fmaxf(mm, __shfl_xor(mm, o));
        if (lane == 0) rtmp[w] = mm;
    }
    __syncthreads();
    const float m_p = fmaxf(fmaxf(rtmp[0], rtmp[1]), fmaxf(rtmp[2], rtmp[3]));
    if (tid < 256) {
        const float e = __expf(sx[tid] - m_p);
        ex[tid] = e;
        float ss = e;
#pragma unroll
        for (int o = 32; o > 0; o >>= 1) ss += __shfl_xor(ss, o);
        if (lane == 0) rtmp[4 + w] = ss;
    }
    __syncthreads();   // publishes ex[] and partial sums
    if (tid == 0) {
        stats[blockIdx.x * 2 + 0] = m_p;
        stats[blockIdx.x * 2 + 1] = rtmp[4] + rtmp[5] + rtmp[6] + rtmp[7];
    }

    // ---- partial context: ctx_p[512] = sum_l ex[l] * E[r0+l, :] ----
    // 4 row-groups of 64 x 128 col4-threads; E slice re-read f32 (L2/L3-hot).
    // Two independent accumulator chains (even/odd rows) halve the dependent
    // FMA-chain stall; unroll-8 keeps 16 loads in flight.
    {
        const int g = tid >> 7, col4 = tid & 127;
        const float* Ep = E + (size_t)(r0 + g * 64) * ENC_D + col4 * 4;
        f32x4 accA = {0.f, 0.f, 0.f, 0.f};
        f32x4 accB = {0.f, 0.f, 0.f, 0.f};
#pragma unroll 8
        for (int l = 0; l < 64; l += 2) {
            const float4 eA = *(const float4*)(Ep + (size_t)l * ENC_D);
            const float4 eB = *(const float4*)(Ep + (size_t)(l + 1) * ENC_D);
            const float wA = ex[g * 64 + l];
            const float wB = ex[g * 64 + l + 1];
            accA[0] += wA * eA.x; accA[1] += wA * eA.y;
            accA[2] += wA * eA.z; accA[3] += wA * eA.w;
            accB[0] += wB * eB.x; accB[1] += wB * eB.y;
            accB[2] += wB * eB.z; accB[3] += wB * eB.w;
        }
        f32x4 acc;
        acc[0] = accA[0] + accB[0]; acc[1] = accA[1] + accB[1];
        acc[2] = accA[2] + accB[2]; acc[3] = accA[3] + accB[3];
        if (g > 0) *(f32x4*)(&red[g - 1][col4 * 4]) = acc;
        __syncthreads();
        if (g == 0) {
            const f32x4 r1 = *(const f32x4*)(&red[0][col4 * 4]);
            const f32x4 r2 = *(const f32x4*)(&red[1][col4 * 4]);
            const f32x4 r3 = *(const f32x4*)(&red[2][col4 * 4]);
            acc[0] += r1[0] + r2[0] + r3[0];
            acc[1] += r1[1] + r2[1] + r3[1];
            acc[2] += r1[2] + r2[2] + r3[2];
            acc[3] += r1[3] + r2[3] + r3[3];
            *(f32x4*)(ctxp + (size_t)blockIdx.x * 512 + col4 * 4) = acc;
        }
    }
}

// ---------------------------------------------------------------------------
// Kernel 3: combine the 4 per-batch partials with max-rescaling.
// out[b,:] = sum_p ctx_p * e^(m_p - m) / sum_p Z_p * e^(m_p - m).
// 64 blocks x 128 threads, ~1 MB read, trivial.
// ---------------------------------------------------------------------------
__global__ __launch_bounds__(128) void k_final(const float* __restrict__ ctxp,
                                               const float* __restrict__ stats,
                                               float* __restrict__ out) {
    const int b = blockIdx.x, t = threadIdx.x;
    const float m0 = stats[(b * 4 + 0) * 2], z0 = stats[(b * 4 + 0) * 2 + 1];
    const float m1 = stats[(b * 4 + 1) * 2], z1 = stats[(b * 4 + 1) * 2 + 1];
    const float m2 = stats[(b * 4 + 2) * 2], z2 = stats[(b * 4 + 2) * 2 + 1];
    const float m3 = stats[(b * 4 + 3) * 2], z3 = stats[(b * 4 + 3) * 2 + 1];
    const float m = fmaxf(fmaxf(m0, m1), fmaxf(m2, m3));
    const float a0 = __expf(m0 - m), a1 = __expf(m1 - m);
    const float a2 = __expf(m2 - m), a3 = __expf(m3 - m);
    const float invD = 1.f / (z0 * a0 + z1 * a1 + z2 * a2 + z3 * a3);

    const float4 c0 = *(const float4*)(ctxp + (size_t)(b * 4 + 0) * 512 + t * 4);
    const float4 c1 = *(const float4*)(ctxp + (size_t)(b * 4 + 1) * 512 + t * 4);
    const float4 c2 = *(const float4*)(ctxp + (size_t)(b * 4 + 2) * 512 + t * 4);
    const float4 c3 = *(const float4*)(ctxp + (size_t)(b * 4 + 3) * 512 + t * 4);
    f32x4 o;
    o[0] = (c0.x * a0 + c1.x * a1 + c2.x * a2 + c3.x * a3) * invD;
    o[1] = (c0.y * a0 + c1.y * a1 + c2.y * a2 + c3.y * a3) * invD;
    o[2] = (c0.z * a0 + c1.z * a1 + c2.z * a2 + c3.z * a3) * invD;
    o[3] = (c0.w * a0 + c1.w * a1 + c2.w * a2 + c3.w * a3) * invD;
    *(f32x4*)(out + (size_t)b * ENC_D + t * 4) = o;
}

// ---------------------------------------------------------------------------
extern "C" void kernel_launch(void* const* d_in, const int* in_sizes, int n_in,
                              void* d_out, int out_size, void* d_ws, size_t ws_size,
                              hipStream_t stream) {
    const float* E      = (const float*)d_in[0];
    const float* str    = (const float*)d_in[1];
    const float* cell   = (const float*)d_in[2];
    const float* Wenc   = (const float*)d_in[3];
    const float* b_enc  = (const float*)d_in[4];
    const float* Wstr   = (const float*)d_in[5];
    const float* b_str  = (const float*)d_in[6];
    const float* Wcell  = (const float*)d_in[7];
    const float* b_cell = (const float*)d_in[8];
    const float* Wcomb  = (const float*)d_in[9];
    // d_in[10] = b_comb: uniform pre-softmax shift — no effect, skipped.
    float* out = (float*)d_out;

    char* ws = (char*)d_ws;
    unsigned short* WF = (unsigned short*)ws;                  // 512 KB (frag-linear)
    float* bpart = (float*)(ws + (512 << 10));                 // 1.5 MB
    float* ctxp  = (float*)(ws + (512 << 10) + (1536 << 10));  // 512 KB
    float* stats = (float*)(ws + (512 << 10) + (2048 << 10));  // 2 KB

    k_prep<<<832, 256, 0, stream>>>(Wenc, WF, str, cell, Wstr, Wcell, bpart);
    k_scores<<<NROWS / 256, 512, 0, stream>>>(E, WF, bpart, b_enc, b_str, b_cell, Wcomb, ctxp, stats);
    k_final<<<BATCH, 128, 0, stream>>>(ctxp, stats, out);
}